// Round 1
// baseline (417.735 us; speedup 1.0000x reference)
//
#include <hip/hip_runtime.h>
#include <math.h>

typedef __bf16 bf16x8 __attribute__((ext_vector_type(8)));
typedef float f32x4 __attribute__((ext_vector_type(4)));
typedef unsigned short u16;
typedef unsigned int u32;

// ---------------- helpers ----------------
__device__ __forceinline__ void gl_lds16(const void* g, void* l) {
  __builtin_amdgcn_global_load_lds(
      (const __attribute__((address_space(1))) void*)g,
      (__attribute__((address_space(3))) void*)l, 16, 0, 0);
}

__device__ __forceinline__ u16 f2bf(float x) {           // RNE f32->bf16
  union { float f; u32 u; } v; v.f = x;
  u32 r = v.u + 0x7FFFu + ((v.u >> 16) & 1u);
  return (u16)(r >> 16);
}

__device__ __forceinline__ float gelu_f(float v) {
  return 0.5f * v * (1.0f + erff(v * 0.7071067811865475f));
}

// ---------------- cast fp32 -> bf16 (exact grid: n/1024 blocks, 4 elem/thread) ----------------
__global__ void castbf(const float* __restrict__ s, u16* __restrict__ d) {
  int i = blockIdx.x * 256 + threadIdx.x;
  float4 v = ((const float4*)s)[i];
  uint2 o;
  o.x = (u32)f2bf(v.x) | ((u32)f2bf(v.y) << 16);
  o.y = (u32)f2bf(v.z) | ((u32)f2bf(v.w) << 16);
  ((uint2*)d)[i] = o;
}

// ---------------- LayerNorm over full [P,E] slab per batch ----------------
__global__ void ln_reduce(const float* __restrict__ src, float2* __restrict__ part) {
  int b = blockIdx.y;
  const float4* p = (const float4*)(src + (size_t)b * 2097152 + (size_t)blockIdx.x * 16384);
  float s = 0.f, q = 0.f;
  #pragma unroll
  for (int i = 0; i < 16; i++) {
    float4 v = p[i * 256 + threadIdx.x];
    s += v.x + v.y + v.z + v.w;
    q += v.x * v.x + v.y * v.y + v.z * v.z + v.w * v.w;
  }
  #pragma unroll
  for (int off = 32; off; off >>= 1) { s += __shfl_down(s, off, 64); q += __shfl_down(q, off, 64); }
  __shared__ float ls[4], lq[4];
  int w = threadIdx.x >> 6;
  if ((threadIdx.x & 63) == 0) { ls[w] = s; lq[w] = q; }
  __syncthreads();
  if (threadIdx.x == 0)
    part[b * 128 + blockIdx.x] =
        make_float2(ls[0] + ls[1] + ls[2] + ls[3], lq[0] + lq[1] + lq[2] + lq[3]);
}

__global__ void ln_final(const float2* __restrict__ part, float2* __restrict__ stats) {
  int b = blockIdx.x, t = threadIdx.x;  // block = 64
  float2 a = part[b * 128 + t], c = part[b * 128 + 64 + t];
  float s = a.x + c.x, q = a.y + c.y;
  #pragma unroll
  for (int off = 32; off; off >>= 1) { s += __shfl_down(s, off, 64); q += __shfl_down(q, off, 64); }
  if (t == 0) {
    const float inv = 1.0f / 2097152.0f;
    float mu = s * inv, var = q * inv - mu * mu;
    stats[b] = make_float2(mu, rsqrtf(var + 1e-5f));
  }
}

__global__ void ln_apply(const float* __restrict__ src, const float* __restrict__ g,
                         const float* __restrict__ bta, const float2* __restrict__ stats,
                         u16* __restrict__ dst) {
  int i = blockIdx.x * 256 + threadIdx.x;  // float4 index, 1048576 total
  int b = i >= 524288;
  float2 st = stats[b];
  int r = i - b * 524288;
  float4 v = ((const float4*)src)[i];
  float4 gv = ((const float4*)g)[r];
  float4 bv = ((const float4*)bta)[r];
  float h0 = (v.x - st.x) * st.y * gv.x + bv.x;
  float h1 = (v.y - st.x) * st.y * gv.y + bv.y;
  float h2 = (v.z - st.x) * st.y * gv.z + bv.z;
  float h3 = (v.w - st.x) * st.y * gv.w + bv.w;
  uint2 o;
  o.x = (u32)f2bf(h0) | ((u32)f2bf(h1) << 16);
  o.y = (u32)f2bf(h2) | ((u32)f2bf(h3) << 16);
  ((uint2*)dst)[i] = o;
}

// ---------------- GEMM: out[m,n] = sum_k A[m,k]*B[n,k]  (B given row-major [N,K]) ----------------
// MODE 0: store bf16.  MODE 1: gelu(x+bias) -> bf16.  MODE 2: gelu(x+bias)+res -> fp32.
template <int MODE>
__global__ __launch_bounds__(256, 2)
void gemm_bt(const u16* __restrict__ A, const u16* __restrict__ Bm,
             const float* __restrict__ bias, const float* __restrict__ res,
             float* __restrict__ outf, u16* __restrict__ outb,
             int M, int N, int K) {
  __shared__ u16 As[128 * 32], Bs[128 * 32];
  const int tid = threadIdx.x;
  const int m0 = blockIdx.y * 128, n0 = blockIdx.x * 128;
  const int lane = tid & 63, w = tid >> 6;
  const int wm = (w >> 1) * 64, wn = (w & 1) * 64;
  const int c = lane & 15, quad = lane >> 4;
  const int arow = tid >> 2, acol = (tid & 3) * 8;

  const u16* gA = A + (size_t)(m0 + arow) * K + acol;
  const u16* gB = Bm + (size_t)(n0 + arow) * K + acol;
  u16* lA = As + tid * 8;
  u16* lB = Bs + tid * 8;

  f32x4 acc[4][4] = {};
  for (int kt = 0; kt < K; kt += 32) {
    gl_lds16(gA, lA);
    gl_lds16(gA + (size_t)64 * K, lA + 64 * 32);
    gl_lds16(gB, lB);
    gl_lds16(gB + (size_t)64 * K, lB + 64 * 32);
    gA += 32; gB += 32;
    __syncthreads();
    bf16x8 af[4], bf[4];
    #pragma unroll
    for (int i = 0; i < 4; i++) {
      af[i] = *(const bf16x8*)&As[(wm + i * 16 + c) * 32 + quad * 8];
      bf[i] = *(const bf16x8*)&Bs[(wn + i * 16 + c) * 32 + quad * 8];
    }
    #pragma unroll
    for (int i = 0; i < 4; i++)
      #pragma unroll
      for (int j = 0; j < 4; j++)
        acc[i][j] = __builtin_amdgcn_mfma_f32_16x16x32_bf16(af[i], bf[j], acc[i][j], 0, 0, 0);
    __syncthreads();
  }
  #pragma unroll
  for (int i = 0; i < 4; i++) {
    const int row0 = m0 + wm + i * 16 + quad * 4;
    #pragma unroll
    for (int j = 0; j < 4; j++) {
      const int col = n0 + wn + j * 16 + c;
      #pragma unroll
      for (int r = 0; r < 4; r++) {
        float v = acc[i][j][r];
        size_t oi = (size_t)(row0 + r) * N + col;
        if (MODE == 1 || MODE == 2) v = gelu_f(v + bias[col]);
        if (MODE == 2) outf[oi] = v + res[oi];
        else           outb[oi] = f2bf(v);
      }
    }
  }
}

// ---------------- transpose V: vt[bh][d][p] = qkv[b*P+p][2E + h*64 + d] ----------------
__global__ void vtrans(const u16* __restrict__ qkv, u16* __restrict__ vt) {
  __shared__ u16 t[64 * 66];
  int bh = blockIdx.y, p0 = blockIdx.x * 64;
  int b = bh >> 3, h = bh & 7;
  const u16* src = qkv + ((size_t)(b * 4096 + p0)) * 1536 + 1024 + h * 64;
  int tid = threadIdx.x;
  #pragma unroll
  for (int j = 0; j < 16; j++) {
    int idx = j * 256 + tid;
    int p = idx >> 6, d = idx & 63;
    t[d * 66 + p] = src[(size_t)p * 1536 + d];
  }
  __syncthreads();
  u16* dst = vt + (size_t)bh * 64 * 4096 + p0;
  #pragma unroll
  for (int j = 0; j < 16; j++) {
    int idx = j * 256 + tid;
    int d = idx >> 6, p = idx & 63;
    dst[(size_t)d * 4096 + p] = t[d * 66 + p];
  }
}

// ---------------- attention pass 1: rl[bh][k] = 1 / sum_q exp(q.k/8) ----------------
__global__ __launch_bounds__(256, 2)
void attn_pass1(const u16* __restrict__ qkv, float* __restrict__ rl) {
  __shared__ u16 Ks[2 * 128 * 32], Qs[2 * 128 * 32];
  __shared__ float colsum[128];
  const int tid = threadIdx.x;
  const int bh = blockIdx.y, b = bh >> 3, h = bh & 7;
  const int k0 = blockIdx.x * 128;
  const int lane = tid & 63, w = tid >> 6;
  const int wm = (w >> 1) * 64, wn = (w & 1) * 64;
  const int c = lane & 15, quad = lane >> 4;
  const int arow = tid >> 2, acol = (tid & 3) * 8;
  const u16* Kg = qkv + ((size_t)(b * 4096 + k0)) * 1536 + 512 + h * 64;
  const u16* Qg = qkv + ((size_t)(b * 4096)) * 1536 + h * 64;

  #pragma unroll
  for (int ks = 0; ks < 2; ks++)
    #pragma unroll
    for (int rr = 0; rr < 128; rr += 64)
      gl_lds16(Kg + (size_t)(rr + arow) * 1536 + ks * 32 + acol,
               Ks + ks * 4096 + (rr + arow) * 32 + acol);
  if (tid < 128) colsum[tid] = 0.f;

  float sacc[4] = {0.f, 0.f, 0.f, 0.f};
  for (int qt = 0; qt < 32; qt++) {
    #pragma unroll
    for (int ks = 0; ks < 2; ks++)
      #pragma unroll
      for (int rr = 0; rr < 128; rr += 64)
        gl_lds16(Qg + (size_t)(qt * 128 + rr + arow) * 1536 + ks * 32 + acol,
                 Qs + ks * 4096 + (rr + arow) * 32 + acol);
    __syncthreads();
    f32x4 acc[4][4] = {};
    #pragma unroll
    for (int ks = 0; ks < 2; ks++) {
      bf16x8 af[4], bf[4];
      #pragma unroll
      for (int i = 0; i < 4; i++) {
        af[i] = *(const bf16x8*)&Qs[ks * 4096 + (wm + i * 16 + c) * 32 + quad * 8];
        bf[i] = *(const bf16x8*)&Ks[ks * 4096 + (wn + i * 16 + c) * 32 + quad * 8];
      }
      #pragma unroll
      for (int i = 0; i < 4; i++)
        #pragma unroll
        for (int j = 0; j < 4; j++)
          acc[i][j] = __builtin_amdgcn_mfma_f32_16x16x32_bf16(af[i], bf[j], acc[i][j], 0, 0, 0);
    }
    #pragma unroll
    for (int j = 0; j < 4; j++) {
      float t = 0.f;
      #pragma unroll
      for (int i = 0; i < 4; i++)
        #pragma unroll
        for (int r = 0; r < 4; r++)
          t += __expf(acc[i][j][r] * 0.125f);
      sacc[j] += t;
    }
    __syncthreads();
  }
  #pragma unroll
  for (int j = 0; j < 4; j++) {
    float v = sacc[j];
    v += __shfl_xor(v, 16, 64);
    v += __shfl_xor(v, 32, 64);
    if (quad == 0) atomicAdd(&colsum[wn + j * 16 + c], v);
  }
  __syncthreads();
  if (tid < 128) rl[(size_t)bh * 4096 + k0 + tid] = 1.0f / colsum[tid];
}

// ---------------- attention pass 2: out1 = x + P@V ----------------
__global__ __launch_bounds__(256, 2)
void attn_pass2(const u16* __restrict__ qkv, const u16* __restrict__ vt,
                const float* __restrict__ rl, const float* __restrict__ x,
                float* __restrict__ out1) {
  __shared__ u16 Qs[2 * 128 * 32];  // 16 KB
  __shared__ u16 Ks[2 * 128 * 32];  // 16 KB
  __shared__ u16 Vs[4 * 64 * 32];   // 16 KB, [d][k] panels
  __shared__ u16 Ps[4 * 128 * 32];  // 32 KB, [q][k] panels
  const int tid = threadIdx.x;
  const int bh = blockIdx.y, b = bh >> 3, h = bh & 7;
  const int q0 = blockIdx.x * 128;
  const int lane = tid & 63, w = tid >> 6;
  const int wm = (w >> 1) * 64, wn = (w & 1) * 64;  // S tiling
  const int wn2 = (w & 1) * 32;                     // PV d tiling
  const int c = lane & 15, quad = lane >> 4;
  const int arow = tid >> 2, acol = (tid & 3) * 8;
  const u16* Qg = qkv + ((size_t)(b * 4096 + q0)) * 1536 + h * 64;
  const u16* Kg = qkv + ((size_t)(b * 4096)) * 1536 + 512 + h * 64;
  const u16* Vg = vt + (size_t)bh * 64 * 4096;
  const float* rlg = rl + (size_t)bh * 4096;

  #pragma unroll
  for (int ks = 0; ks < 2; ks++)
    #pragma unroll
    for (int rr = 0; rr < 128; rr += 64)
      gl_lds16(Qg + (size_t)(rr + arow) * 1536 + ks * 32 + acol,
               Qs + ks * 4096 + (rr + arow) * 32 + acol);

  f32x4 oacc[4][2] = {};
  for (int kt = 0; kt < 32; kt++) {
    const int k0 = kt * 128;
    #pragma unroll
    for (int ks = 0; ks < 2; ks++)
      #pragma unroll
      for (int rr = 0; rr < 128; rr += 64)
        gl_lds16(Kg + (size_t)(k0 + rr + arow) * 1536 + ks * 32 + acol,
                 Ks + ks * 4096 + (rr + arow) * 32 + acol);
    #pragma unroll
    for (int kp = 0; kp < 4; kp++)
      gl_lds16(Vg + (size_t)arow * 4096 + k0 + kp * 32 + acol,
               Vs + kp * 2048 + arow * 32 + acol);
    __syncthreads();
    // ---- S = Q K^T
    f32x4 sacc[4][4] = {};
    #pragma unroll
    for (int ks = 0; ks < 2; ks++) {
      bf16x8 af[4], bf[4];
      #pragma unroll
      for (int i = 0; i < 4; i++) {
        af[i] = *(const bf16x8*)&Qs[ks * 4096 + (wm + i * 16 + c) * 32 + quad * 8];
        bf[i] = *(const bf16x8*)&Ks[ks * 4096 + (wn + i * 16 + c) * 32 + quad * 8];
      }
      #pragma unroll
      for (int i = 0; i < 4; i++)
        #pragma unroll
        for (int j = 0; j < 4; j++)
          sacc[i][j] = __builtin_amdgcn_mfma_f32_16x16x32_bf16(af[i], bf[j], sacc[i][j], 0, 0, 0);
    }
    // ---- P = exp(S/8) * rl[k], into LDS (C-layout -> [q][k] panels)
    float rlv[4];
    #pragma unroll
    for (int j = 0; j < 4; j++) rlv[j] = rlg[k0 + wn + j * 16 + c];
    #pragma unroll
    for (int i = 0; i < 4; i++)
      #pragma unroll
      for (int j = 0; j < 4; j++) {
        const int kk = wn + j * 16 + c;
        u16* pp = Ps + (kk >> 5) * 4096 + (kk & 31);
        #pragma unroll
        for (int r = 0; r < 4; r++) {
          const int qq = wm + i * 16 + quad * 4 + r;
          pp[qq * 32] = f2bf(__expf(sacc[i][j][r] * 0.125f) * rlv[j]);
        }
      }
    __syncthreads();
    // ---- O += P V
    #pragma unroll
    for (int ks = 0; ks < 4; ks++) {
      bf16x8 pf[4], vf[2];
      #pragma unroll
      for (int i = 0; i < 4; i++)
        pf[i] = *(const bf16x8*)&Ps[ks * 4096 + (wm + i * 16 + c) * 32 + quad * 8];
      #pragma unroll
      for (int j = 0; j < 2; j++)
        vf[j] = *(const bf16x8*)&Vs[ks * 2048 + (wn2 + j * 16 + c) * 32 + quad * 8];
      #pragma unroll
      for (int i = 0; i < 4; i++)
        #pragma unroll
        for (int j = 0; j < 2; j++)
          oacc[i][j] = __builtin_amdgcn_mfma_f32_16x16x32_bf16(pf[i], vf[j], oacc[i][j], 0, 0, 0);
    }
    __syncthreads();
  }
  // ---- epilogue: out1 = x + O
  #pragma unroll
  for (int i = 0; i < 4; i++)
    #pragma unroll
    for (int j = 0; j < 2; j++)
      #pragma unroll
      for (int r = 0; r < 4; r++) {
        const int qq = q0 + wm + i * 16 + quad * 4 + r;
        const int dd = wn2 + j * 16 + c;
        size_t oi = ((size_t)(b * 4096 + qq)) * 512 + h * 64 + dd;
        out1[oi] = x[oi] + oacc[i][j][r];
      }
}

// ---------------- launch ----------------
extern "C" void kernel_launch(void* const* d_in, const int* in_sizes, int n_in,
                              void* d_out, int out_size, void* d_ws, size_t ws_size,
                              hipStream_t stream) {
  const float* x  = (const float*)d_in[0];
  const float* g1 = (const float*)d_in[1];
  const float* b1 = (const float*)d_in[2];
  const float* W1 = (const float*)d_in[3];
  const float* g2 = (const float*)d_in[4];
  const float* b2 = (const float*)d_in[5];
  const float* Wa = (const float*)d_in[6];
  const float* ba = (const float*)d_in[7];
  const float* Wb = (const float*)d_in[8];
  const float* bb = (const float*)d_in[9];
  float* out = (float*)d_out;

  char* ws = (char*)d_ws;
  u16* w1b   = (u16*)(ws);                       // 1.5 MB
  u16* wab   = (u16*)(ws + 1572864);             // 1.5 MB
  u16* wbb   = (u16*)(ws + 3145728);             // 1.5 MB
  u16* h1    = (u16*)(ws + 4718592);             // 8 MB
  u16* qkv   = (u16*)(ws + 13107200);            // 24 MB
  u16* vt    = (u16*)(ws + 38273024);            // 8 MB
  u16* h2    = (u16*)(ws + 46661632);            // 8 MB
  u16* mid   = (u16*)(ws + 55050240);            // 24 MB
  float* rl  = (float*)(ws + 80216064);          // 256 KB
  float* o1  = (float*)(ws + 80478208);          // 16 MB
  float2* part  = (float2*)(ws + 97255424);      // 2 KB
  float2* stats = (float2*)(ws + 97257472);      // 16 B

  castbf<<<768, 256, 0, stream>>>(W1, w1b);
  castbf<<<768, 256, 0, stream>>>(Wa, wab);
  castbf<<<768, 256, 0, stream>>>(Wb, wbb);

  ln_reduce<<<dim3(128, 2), 256, 0, stream>>>(x, part);
  ln_final<<<2, 64, 0, stream>>>(part, stats);
  ln_apply<<<4096, 256, 0, stream>>>(x, g1, b1, stats, h1);

  gemm_bt<0><<<dim3(12, 64), 256, 0, stream>>>(h1, w1b, nullptr, nullptr, nullptr, qkv,
                                               8192, 1536, 512);
  vtrans<<<dim3(64, 16), 256, 0, stream>>>(qkv, vt);
  attn_pass1<<<dim3(32, 16), 256, 0, stream>>>(qkv, rl);
  attn_pass2<<<dim3(32, 16), 256, 0, stream>>>(qkv, vt, rl, x, o1);

  ln_reduce<<<dim3(128, 2), 256, 0, stream>>>(o1, part);
  ln_final<<<2, 64, 0, stream>>>(part, stats);
  ln_apply<<<4096, 256, 0, stream>>>(o1, g2, b2, stats, h2);

  gemm_bt<1><<<dim3(12, 64), 256, 0, stream>>>(h2, wab, ba, nullptr, nullptr, mid,
                                               8192, 1536, 512);
  gemm_bt<2><<<dim3(4, 64), 256, 0, stream>>>(mid, wbb, bb, o1, out, nullptr,
                                              8192, 512, 1536);
}